// Round 12
// baseline (33.474 us; speedup 1.0000x reference)
//
#include <hip/hip_runtime.h>
#include <math.h>

// YOLO box decode: x[B=32, A*(NC+5)=255, G=52, G=52] f32 ->
// out[B, A*G*G=8112, 85] f32  (+ trailing scalar 0 from the tuple return).
//
// R1: TILE 64 (7 blocks/CU), float4 reads, native exp.      47.2 -> 37.6 us
// R3/R4: unrolled 6-deep load/store phases (MLP), NT stores. 37.6 -> 35.7 us
// R5: TILE=52 FAILED (38.7): misaligned 208B segments, FETCH +22%.
// R6: wave-private 16-cell tiles FAILED (39.2): 64B read segments.
// R7/R8: 2-tile pipeline FAILED (415/165us): VGPR spills to scratch.
// R9: spill-free pipeline = +1% (35.3): latency is NOT the constraint.
// R10: 512B read segments (block=512, TILE=128) WIN: 35.3 -> 33.2 us.
// R11: bijective XCD swizzle WIN: 33.2 -> 31.3 us; FETCH 48.8->43.1 MB.
// R12: persistent 2-tile chaining: 1056 blocks, each does two consecutive
//     tiles (pairs never straddle a panel; 22 tiles/panel is even).
//     Halves launch/drain churn, doubles per-block stream run-length.
//     Body identical to R11; one extra barrier for LDS reuse.

#define NB    32
#define NA    3
#define NCH   85
#define GG    52
#define CELLS (GG * GG)          // 2704
#define TILE  128                // cells per tile
#define NTILES ((CELLS + TILE - 1) / TILE)   // 22 (21 full + tail of 16)
#define NWORK (NTILES * NA * NB) // 2112 logical work items
#define NBLK  (NWORK / 2)        // 1056 blocks, 2 works each; 1056 % 8 == 0
#define STRIDEF 8.0f

typedef float f32x4 __attribute__((ext_vector_type(4)));

__device__ __forceinline__ float sigm(float v) {
    return __fdividef(1.0f, 1.0f + __expf(-v));
}

__global__ __launch_bounds__(512, 6) void yolo_decode(const float* __restrict__ x,
                                                      float* __restrict__ out,
                                                      long long out_size) {
    __shared__ __align__(16) float lds[TILE * NCH];   // 43.52 KB -> 3 blocks/CU

    // XCD-aware bijective swizzle at block level: XCD k gets blocks
    // [k*132, (k+1)*132) -> works [k*264, (k+1)*264) = 12 full panels.
    const int wg    = blockIdx.x;
    const int blk   = (wg & 7) * (NBLK / 8) + (wg >> 3);
    const int work0 = blk * 2;
    const int ab    = work0 / NTILES;                 // same for both works
    const int a     = ab % NA;
    const int b     = ab / NA;
    const int tile0 = work0 - ab * NTILES;            // even: 0,2,...,20

    const int tid = threadIdx.x;

    const float aw = (a == 0) ? 10.0f : (a == 1) ? 16.0f : 33.0f;
    const float ah = (a == 0) ? 13.0f : (a == 1) ? 30.0f : 23.0f;

    // fold the tuple's trailing scalar 0 into this kernel
    const long long MAIN = (long long)NB * NA * CELLS * NCH;
    if (blk == 0 && tid == 0 && out_size > MAIN) {
        for (long long i = MAIN; i < out_size; ++i) out[i] = 0.0f;
    }

    const float* xbase = x + ((size_t)(b * NA + a) * NCH) * CELLS;
    float* obase = out + ((size_t)(b * NA + a) * CELLS) * NCH;

    // 512 threads: 16 channel-groups x 32 cell-slots.
    // Each half-wave (32 lanes) reads one contiguous 512B segment per load.
    const int start = tid >> 5;                       // channel group 0..15
    const int c4    = (tid & 31) * 4;                 // local cell (x4), 0..124
    const bool has6 = (start < 5);

    #pragma unroll 1
    for (int it = 0; it < 2; ++it) {
        const int tile  = tile0 + it;
        const int cell0 = tile * TILE;
        const int ncell = min(TILE, CELLS - cell0);   // 128 or 16 (tile 21)

        if (it) __syncthreads();                      // prev flush-reads done

        if (c4 < ncell) {
            const float* xb = xbase + cell0;
            float gx[4], gy[4];
            #pragma unroll
            for (int j = 0; j < 4; ++j) {
                const int cell = cell0 + c4 + j;
                gx[j] = (float)(cell % GG);
                gy[j] = (float)(cell / GG);
            }

            // channels: start + 16k; k=0..4 always (ch<=79), k=5 iff start<5.
            // All 5-6 loads issued before any use (MLP within thread).
            f32x4 v0 = *(const f32x4*)(xb + (size_t)(start     ) * CELLS + c4);
            f32x4 v1 = *(const f32x4*)(xb + (size_t)(start + 16) * CELLS + c4);
            f32x4 v2 = *(const f32x4*)(xb + (size_t)(start + 32) * CELLS + c4);
            f32x4 v3 = *(const f32x4*)(xb + (size_t)(start + 48) * CELLS + c4);
            f32x4 v4 = *(const f32x4*)(xb + (size_t)(start + 64) * CELLS + c4);
            f32x4 v5 = v4;
            if (has6) v5 = *(const f32x4*)(xb + (size_t)(start + 80) * CELLS + c4);

            // channel 'start' (only one that can be special)
            {
                float r0 = v0.x, r1 = v0.y, r2 = v0.z, r3 = v0.w;
                if (start == 0) {
                    r0 = (sigm(r0) + gx[0]) * STRIDEF;
                    r1 = (sigm(r1) + gx[1]) * STRIDEF;
                    r2 = (sigm(r2) + gx[2]) * STRIDEF;
                    r3 = (sigm(r3) + gx[3]) * STRIDEF;
                } else if (start == 1) {
                    r0 = (sigm(r0) + gy[0]) * STRIDEF;
                    r1 = (sigm(r1) + gy[1]) * STRIDEF;
                    r2 = (sigm(r2) + gy[2]) * STRIDEF;
                    r3 = (sigm(r3) + gy[3]) * STRIDEF;
                } else if (start == 2) {
                    r0 = __expf(r0) * aw; r1 = __expf(r1) * aw;
                    r2 = __expf(r2) * aw; r3 = __expf(r3) * aw;
                } else if (start == 3) {
                    r0 = __expf(r0) * ah; r1 = __expf(r1) * ah;
                    r2 = __expf(r2) * ah; r3 = __expf(r3) * ah;
                } else {
                    r0 = sigm(r0); r1 = sigm(r1); r2 = sigm(r2); r3 = sigm(r3);
                }
                lds[(c4    ) * NCH + start] = r0;
                lds[(c4 + 1) * NCH + start] = r1;
                lds[(c4 + 2) * NCH + start] = r2;
                lds[(c4 + 3) * NCH + start] = r3;
            }
            {
                const int ch = start + 16;
                lds[(c4    ) * NCH + ch] = sigm(v1.x);
                lds[(c4 + 1) * NCH + ch] = sigm(v1.y);
                lds[(c4 + 2) * NCH + ch] = sigm(v1.z);
                lds[(c4 + 3) * NCH + ch] = sigm(v1.w);
            }
            {
                const int ch = start + 32;
                lds[(c4    ) * NCH + ch] = sigm(v2.x);
                lds[(c4 + 1) * NCH + ch] = sigm(v2.y);
                lds[(c4 + 2) * NCH + ch] = sigm(v2.z);
                lds[(c4 + 3) * NCH + ch] = sigm(v2.w);
            }
            {
                const int ch = start + 48;
                lds[(c4    ) * NCH + ch] = sigm(v3.x);
                lds[(c4 + 1) * NCH + ch] = sigm(v3.y);
                lds[(c4 + 2) * NCH + ch] = sigm(v3.z);
                lds[(c4 + 3) * NCH + ch] = sigm(v3.w);
            }
            {
                const int ch = start + 64;
                lds[(c4    ) * NCH + ch] = sigm(v4.x);
                lds[(c4 + 1) * NCH + ch] = sigm(v4.y);
                lds[(c4 + 2) * NCH + ch] = sigm(v4.z);
                lds[(c4 + 3) * NCH + ch] = sigm(v4.w);
            }
            if (has6) {
                const int ch = start + 80;
                lds[(c4    ) * NCH + ch] = sigm(v5.x);
                lds[(c4 + 1) * NCH + ch] = sigm(v5.y);
                lds[(c4 + 2) * NCH + ch] = sigm(v5.z);
                lds[(c4 + 3) * NCH + ch] = sigm(v5.w);
            }
        }
        __syncthreads();

        // coalesced writeback: ncell*85 floats contiguous; 1KB/wave/instr.
        // total4 = 2720 (full) or 340 (tail). All ds_reads, then NT stores.
        float* ob = obase + (size_t)cell0 * NCH;
        const int total4 = (ncell * NCH) >> 2;
        const f32x4* l4 = (const f32x4*)lds;
        f32x4* o4 = (f32x4*)ob;

        f32x4 t0 = {}, t1 = {}, t2 = {}, t3 = {}, t4 = {}, t5 = {};
        const int j0 = tid, j1 = tid + 512, j2 = tid + 1024;
        const int j3 = tid + 1536, j4 = tid + 2048, j5 = tid + 2560;
        if (j0 < total4) t0 = l4[j0];
        if (j1 < total4) t1 = l4[j1];
        if (j2 < total4) t2 = l4[j2];
        if (j3 < total4) t3 = l4[j3];
        if (j4 < total4) t4 = l4[j4];
        if (j5 < total4) t5 = l4[j5];
        if (j0 < total4) __builtin_nontemporal_store(t0, &o4[j0]);
        if (j1 < total4) __builtin_nontemporal_store(t1, &o4[j1]);
        if (j2 < total4) __builtin_nontemporal_store(t2, &o4[j2]);
        if (j3 < total4) __builtin_nontemporal_store(t3, &o4[j3]);
        if (j4 < total4) __builtin_nontemporal_store(t4, &o4[j4]);
        if (j5 < total4) __builtin_nontemporal_store(t5, &o4[j5]);
    }
}

extern "C" void kernel_launch(void* const* d_in, const int* in_sizes, int n_in,
                              void* d_out, int out_size, void* d_ws, size_t ws_size,
                              hipStream_t stream) {
    const float* x = (const float*)d_in[0];
    float* out = (float*)d_out;

    yolo_decode<<<dim3(NBLK), 512, 0, stream>>>(x, out, (long long)out_size);
}

// Round 13
// 31.372 us; speedup vs baseline: 1.0670x; 1.0670x over previous
//
#include <hip/hip_runtime.h>
#include <math.h>

// YOLO box decode: x[B=32, A*(NC+5)=255, G=52, G=52] f32 ->
// out[B, A*G*G=8112, 85] f32  (+ trailing scalar 0 from the tuple return).
//
// FINAL STRUCTURE (= R11 best, 31.3 us):
// R1: TILE 64 (7 blocks/CU), float4 reads, native exp.      47.2 -> 37.6 us
// R3/R4: unrolled 6-deep load/store phases (MLP), NT stores. 37.6 -> 35.7 us
// R5: TILE=52 FAILED (38.7): misaligned 208B segments, FETCH +22%.
// R6: wave-private 16-cell tiles FAILED (39.2): 64B read segments.
// R7/R8: 2-tile pipeline FAILED (415/165us): VGPR spills to scratch.
// R9: spill-free pipeline = +1% (35.3): latency is NOT the constraint.
// R10: 512B read segments (block=512, TILE=128) WIN: 35.3 -> 33.2 us.
// R11: bijective XCD swizzle WIN: 33.2 -> 31.3 us; FETCH 48.8->43.1 MB.
// R12: persistent 2-tile chaining FAILED (33.5): serial barrier idles
//     block during flush-drain; fewer independent blocks hurts.
// Roofline: 175.5MB logical / 31.3us = 5.6 TB/s = 89% of 6.29 TB/s copy
// ceiling (HBM 130MB @ 4.2 TB/s + ~45MB L3-served reads via NT stores).

#define NB    32
#define NA    3
#define NCH   85
#define GG    52
#define CELLS (GG * GG)          // 2704
#define TILE  128                // cells per block
#define NTILES ((CELLS + TILE - 1) / TILE)   // 22 (21 full + tail of 16)
#define NWG   (NTILES * NA * NB) // 2112
#define STRIDEF 8.0f

typedef float f32x4 __attribute__((ext_vector_type(4)));

__device__ __forceinline__ float sigm(float v) {
    return __fdividef(1.0f, 1.0f + __expf(-v));
}

__global__ __launch_bounds__(512, 6) void yolo_decode(const float* __restrict__ x,
                                                      float* __restrict__ out,
                                                      long long out_size) {
    __shared__ __align__(16) float lds[TILE * NCH];   // 43.52 KB -> 3 blocks/CU

    // XCD-aware bijective swizzle: HW round-robins linear wg across 8 XCDs;
    // give XCD k the contiguous logical range [k*264, (k+1)*264) = 12 panels.
    const int wg   = blockIdx.x;
    const int work = (wg & 7) * (NWG / 8) + (wg >> 3);
    const int tile = work % NTILES;
    const int ab   = work / NTILES;                   // 0..95
    const int a    = ab % NA;
    const int b    = ab / NA;

    const int cell0 = tile * TILE;
    const int ncell = min(TILE, CELLS - cell0);       // 128 or 16

    const int tid  = threadIdx.x;

    const float aw = (a == 0) ? 10.0f : (a == 1) ? 16.0f : 33.0f;
    const float ah = (a == 0) ? 13.0f : (a == 1) ? 30.0f : 23.0f;

    // fold the tuple's trailing scalar 0 into this kernel
    const long long MAIN = (long long)NB * NA * CELLS * NCH;
    if (work == 0 && tid == 0 && out_size > MAIN) {
        for (long long i = MAIN; i < out_size; ++i) out[i] = 0.0f;
    }

    const float* xb = x + ((size_t)(b * NA + a) * NCH) * CELLS + cell0;

    // 512 threads: 16 channel-groups x 32 cell-slots.
    // Each half-wave (32 lanes) reads one contiguous 512B segment per load.
    const int start = tid >> 5;                       // channel group 0..15
    const int c4    = (tid & 31) * 4;                 // local cell (x4), 0..124
    const bool has6 = (start < 5);

    if (c4 < ncell) {
        float gx[4], gy[4];
        #pragma unroll
        for (int j = 0; j < 4; ++j) {
            const int cell = cell0 + c4 + j;
            gx[j] = (float)(cell % GG);
            gy[j] = (float)(cell / GG);
        }

        // channels: start + 16k; k=0..4 always (ch<=79), k=5 iff start<5.
        // All 5-6 loads issued before any use (MLP within thread).
        f32x4 v0 = *(const f32x4*)(xb + (size_t)(start     ) * CELLS + c4);
        f32x4 v1 = *(const f32x4*)(xb + (size_t)(start + 16) * CELLS + c4);
        f32x4 v2 = *(const f32x4*)(xb + (size_t)(start + 32) * CELLS + c4);
        f32x4 v3 = *(const f32x4*)(xb + (size_t)(start + 48) * CELLS + c4);
        f32x4 v4 = *(const f32x4*)(xb + (size_t)(start + 64) * CELLS + c4);
        f32x4 v5 = v4;
        if (has6) v5 = *(const f32x4*)(xb + (size_t)(start + 80) * CELLS + c4);

        // channel 'start' (only one that can be special)
        {
            float r0 = v0.x, r1 = v0.y, r2 = v0.z, r3 = v0.w;
            if (start == 0) {
                r0 = (sigm(r0) + gx[0]) * STRIDEF;
                r1 = (sigm(r1) + gx[1]) * STRIDEF;
                r2 = (sigm(r2) + gx[2]) * STRIDEF;
                r3 = (sigm(r3) + gx[3]) * STRIDEF;
            } else if (start == 1) {
                r0 = (sigm(r0) + gy[0]) * STRIDEF;
                r1 = (sigm(r1) + gy[1]) * STRIDEF;
                r2 = (sigm(r2) + gy[2]) * STRIDEF;
                r3 = (sigm(r3) + gy[3]) * STRIDEF;
            } else if (start == 2) {
                r0 = __expf(r0) * aw; r1 = __expf(r1) * aw;
                r2 = __expf(r2) * aw; r3 = __expf(r3) * aw;
            } else if (start == 3) {
                r0 = __expf(r0) * ah; r1 = __expf(r1) * ah;
                r2 = __expf(r2) * ah; r3 = __expf(r3) * ah;
            } else {
                r0 = sigm(r0); r1 = sigm(r1); r2 = sigm(r2); r3 = sigm(r3);
            }
            lds[(c4    ) * NCH + start] = r0;
            lds[(c4 + 1) * NCH + start] = r1;
            lds[(c4 + 2) * NCH + start] = r2;
            lds[(c4 + 3) * NCH + start] = r3;
        }
        {
            const int ch = start + 16;
            lds[(c4    ) * NCH + ch] = sigm(v1.x);
            lds[(c4 + 1) * NCH + ch] = sigm(v1.y);
            lds[(c4 + 2) * NCH + ch] = sigm(v1.z);
            lds[(c4 + 3) * NCH + ch] = sigm(v1.w);
        }
        {
            const int ch = start + 32;
            lds[(c4    ) * NCH + ch] = sigm(v2.x);
            lds[(c4 + 1) * NCH + ch] = sigm(v2.y);
            lds[(c4 + 2) * NCH + ch] = sigm(v2.z);
            lds[(c4 + 3) * NCH + ch] = sigm(v2.w);
        }
        {
            const int ch = start + 48;
            lds[(c4    ) * NCH + ch] = sigm(v3.x);
            lds[(c4 + 1) * NCH + ch] = sigm(v3.y);
            lds[(c4 + 2) * NCH + ch] = sigm(v3.z);
            lds[(c4 + 3) * NCH + ch] = sigm(v3.w);
        }
        {
            const int ch = start + 64;
            lds[(c4    ) * NCH + ch] = sigm(v4.x);
            lds[(c4 + 1) * NCH + ch] = sigm(v4.y);
            lds[(c4 + 2) * NCH + ch] = sigm(v4.z);
            lds[(c4 + 3) * NCH + ch] = sigm(v4.w);
        }
        if (has6) {
            const int ch = start + 80;
            lds[(c4    ) * NCH + ch] = sigm(v5.x);
            lds[(c4 + 1) * NCH + ch] = sigm(v5.y);
            lds[(c4 + 2) * NCH + ch] = sigm(v5.z);
            lds[(c4 + 3) * NCH + ch] = sigm(v5.w);
        }
    }
    __syncthreads();

    // coalesced writeback: ncell*85 floats contiguous; wave writes 1KB/instr.
    // total4 = 2720 (full) or 340 (tail). Issue all ds_reads, then NT stores.
    float* ob = out + ((size_t)((b * NA + a) * CELLS + cell0)) * NCH;
    const int total4 = (ncell * NCH) >> 2;
    const f32x4* l4 = (const f32x4*)lds;
    f32x4* o4 = (f32x4*)ob;

    f32x4 t0 = {}, t1 = {}, t2 = {}, t3 = {}, t4 = {}, t5 = {};
    const int j0 = tid, j1 = tid + 512, j2 = tid + 1024;
    const int j3 = tid + 1536, j4 = tid + 2048, j5 = tid + 2560;
    if (j0 < total4) t0 = l4[j0];
    if (j1 < total4) t1 = l4[j1];
    if (j2 < total4) t2 = l4[j2];
    if (j3 < total4) t3 = l4[j3];
    if (j4 < total4) t4 = l4[j4];
    if (j5 < total4) t5 = l4[j5];
    if (j0 < total4) __builtin_nontemporal_store(t0, &o4[j0]);
    if (j1 < total4) __builtin_nontemporal_store(t1, &o4[j1]);
    if (j2 < total4) __builtin_nontemporal_store(t2, &o4[j2]);
    if (j3 < total4) __builtin_nontemporal_store(t3, &o4[j3]);
    if (j4 < total4) __builtin_nontemporal_store(t4, &o4[j4]);
    if (j5 < total4) __builtin_nontemporal_store(t5, &o4[j5]);
}

extern "C" void kernel_launch(void* const* d_in, const int* in_sizes, int n_in,
                              void* d_out, int out_size, void* d_ws, size_t ws_size,
                              hipStream_t stream) {
    const float* x = (const float*)d_in[0];
    float* out = (float*)d_out;

    yolo_decode<<<dim3(NWG), 512, 0, stream>>>(x, out, (long long)out_size);
}